// Round 1
// baseline (505.624 us; speedup 1.0000x reference)
//
#include <hip/hip_runtime.h>

// ReluTransformer backsubstitution, structure-exploiting version.
// w_lb / w_ub are [N+1, N+1] with: diag top-left NxN block, bias last column,
// last row = e_{N+1}. So the "GEMM" is elementwise scaling + one dot per row.
//
// R = 8192 rows, N = 4096 -> NCOLS = 4097 (odd stride: per-row float4
// alignment rotates mod 4, handled via 4 phase-shifted scale copies in ws).

#define N_IN   4096
#define NCOLS  4097
#define NROWS  8192
#define PAD    4104   // multiple of 8, >= NCOLS

// ws layout: 16 float arrays of PAD elements each:
//   index (s*4 + a)*PAD + i , a: 0=d_lb 1=d_ub 2=b_lb 3=b_ub
//   arr[s][a][i] = base_a[i + s]   (phase-shifted so float4 loads align)
__global__ void extract_scales(const float* __restrict__ w_lb,
                               const float* __restrict__ w_ub,
                               float* __restrict__ ws) {
    int j = blockIdx.x * blockDim.x + threadIdx.x;
    if (j >= NCOLS) return;
    size_t row = (size_t)j * NCOLS;
    float dlb = w_lb[row + j];       // diagonal entry (j==N_IN: w[N,N]=1, unused as diag)
    float dub = w_ub[row + j];
    float blb = w_lb[row + N_IN];    // last-column (bias) entry; blb[N]=w_lb[N,N]=1
    float bub = w_ub[row + N_IN];
#pragma unroll
    for (int s = 0; s < 4; ++s) {
        if (j >= s) {
            int i = j - s;
            ws[(size_t)(s * 4 + 0) * PAD + i] = dlb;
            ws[(size_t)(s * 4 + 1) * PAD + i] = dub;
            ws[(size_t)(s * 4 + 2) * PAD + i] = blb;
            ws[(size_t)(s * 4 + 3) * PAD + i] = bub;
        }
    }
}

__global__ __launch_bounds__(256) void backsub_rows(
        const float* __restrict__ lb, const float* __restrict__ ub,
        const float* __restrict__ ws, float* __restrict__ out) {
    const int r   = blockIdx.x;
    const int tid = threadIdx.x;
    // first column of row r such that (r*NCOLS + j0) % 4 == 0
    const int j0 = (4 - (r & 3)) & 3;
    const size_t row_off = (size_t)r * NCOLS;
    const float* lb_row  = lb + row_off;
    const float* ub_row  = ub + row_off;
    float* olb_row = out + row_off;
    float* oub_row = out + (size_t)NROWS * NCOLS + row_off;

    const int nv = (N_IN - j0) >> 2;               // full float4 chunks, cols < 4096
    const float4* lbv  = (const float4*)(lb_row + j0);
    const float4* ubv  = (const float4*)(ub_row + j0);
    float4*       olbv = (float4*)(olb_row + j0);
    float4*       oubv = (float4*)(oub_row + j0);
    const int s = j0;
    const float4* DL = (const float4*)(ws + (size_t)(s * 4 + 0) * PAD);
    const float4* DU = (const float4*)(ws + (size_t)(s * 4 + 1) * PAD);
    const float4* BL = (const float4*)(ws + (size_t)(s * 4 + 2) * PAD);
    const float4* BU = (const float4*)(ws + (size_t)(s * 4 + 3) * PAD);

    float acc_lb = 0.f, acc_ub = 0.f;

    for (int k = tid; k < nv; k += 256) {
        float4 x  = lbv[k];
        float4 y  = ubv[k];
        float4 dl = DL[k];
        float4 du = DU[k];
        float4 bl = BL[k];
        float4 bu = BU[k];
        float4 ol, ou;
#define COMP(c) do { \
        float px = fmaxf(x.c, 0.f), mx = fminf(x.c, 0.f); \
        ol.c = px * dl.c + mx * du.c; \
        acc_lb = fmaf(px, bl.c, fmaf(mx, bu.c, acc_lb)); \
        float py = fmaxf(y.c, 0.f), my = fminf(y.c, 0.f); \
        ou.c = py * du.c + my * dl.c; \
        acc_ub = fmaf(py, bu.c, fmaf(my, bl.c, acc_ub)); \
    } while (0)
        COMP(x); COMP(y); COMP(z); COMP(w);
#undef COMP
        olbv[k] = ol;
        oubv[k] = ou;
    }

    // scalar head [0, j0) and tail [j0 + 4*nv, NCOLS)
    {
        const int tail = j0 + 4 * nv;
        const int nsc  = j0 + (NCOLS - tail);
        if (tid < nsc) {
            const int j = (tid < j0) ? tid : (tail + tid - j0);
            const float* DL0 = ws + 0 * PAD;   // phase-0 = unshifted arrays
            const float* DU0 = ws + 1 * PAD;
            const float* BL0 = ws + 2 * PAD;
            const float* BU0 = ws + 3 * PAD;
            float dl = DL0[j], du = DU0[j], bl = BL0[j], bu = BU0[j];
            float x = lb_row[j], y = ub_row[j];
            float px = fmaxf(x, 0.f), mx = fminf(x, 0.f);
            if (j < N_IN) olb_row[j] = px * dl + mx * du;
            acc_lb = fmaf(px, bl, fmaf(mx, bu, acc_lb));
            float py = fmaxf(y, 0.f), my = fminf(y, 0.f);
            if (j < N_IN) oub_row[j] = py * du + my * dl;
            acc_ub = fmaf(py, bu, fmaf(my, bl, acc_ub));
        }
    }

    // block reduction: wave shuffle (width 64) then LDS across 4 waves
    for (int o = 32; o > 0; o >>= 1) {
        acc_lb += __shfl_down(acc_lb, o, 64);
        acc_ub += __shfl_down(acc_ub, o, 64);
    }
    __shared__ float red_lb[4];
    __shared__ float red_ub[4];
    const int wave = tid >> 6;
    if ((tid & 63) == 0) {
        red_lb[wave] = acc_lb;
        red_ub[wave] = acc_ub;
    }
    __syncthreads();
    if (tid == 0) {
        olb_row[N_IN] = (red_lb[0] + red_lb[1]) + (red_lb[2] + red_lb[3]);
        oub_row[N_IN] = (red_ub[0] + red_ub[1]) + (red_ub[2] + red_ub[3]);
    }
}

extern "C" void kernel_launch(void* const* d_in, const int* in_sizes, int n_in,
                              void* d_out, int out_size, void* d_ws, size_t ws_size,
                              hipStream_t stream) {
    const float* lb   = (const float*)d_in[0];
    const float* ub   = (const float*)d_in[1];
    const float* w_lb = (const float*)d_in[2];
    const float* w_ub = (const float*)d_in[3];
    float* out = (float*)d_out;
    float* ws  = (float*)d_ws;   // needs 16*PAD*4 = 262,656 bytes

    extract_scales<<<(NCOLS + 255) / 256, 256, 0, stream>>>(w_lb, w_ub, ws);
    backsub_rows<<<NROWS, 256, 0, stream>>>(lb, ub, ws, out);
}